// Round 11
// baseline (467.822 us; speedup 1.0000x reference)
//
#include <hip/hip_runtime.h>

#define N_NODES 50000
#define N_EDGES 800000
#define BN_EPS 1e-5f
#define K_BUCK 196        // dst >> 8 buckets (256 nodes each)
#define PART_B 256        // partition blocks
#define CHUNK 3125        // N_EDGES / PART_B

typedef __attribute__((ext_vector_type(8))) short bshort8;
typedef __attribute__((ext_vector_type(4))) float f32x4;

__device__ inline float bf2f(unsigned int u16) {
    return __uint_as_float(u16 << 16);
}
__device__ inline unsigned short f2bf(float f) {
    unsigned int u = __float_as_uint(f);
    u = (u + 0x7FFFu + ((u >> 16) & 1u)) >> 16;
    return (unsigned short)u;
}

// ---------------- scan helpers ----------------

__device__ inline int block_exscan256(int v, int tid, int* total) {
    int lane = tid & 63;
    int wave = tid >> 6;
    int incl = v;
#pragma unroll
    for (int off = 1; off < 64; off <<= 1) {
        int t = __shfl_up(incl, off, 64);
        if (lane >= off) incl += t;
    }
    __shared__ int wsum[4];
    if (lane == 63) wsum[wave] = incl;
    __syncthreads();
    int w0 = wsum[0], w1 = wsum[1], w2 = wsum[2], w3 = wsum[3];
    __syncthreads();
    int wofs = (wave > 0 ? w0 : 0) + (wave > 1 ? w1 : 0) + (wave > 2 ? w2 : 0);
    *total = w0 + w1 + w2 + w3;
    return wofs + incl - v;
}

__global__ __launch_bounds__(256) void scan_reduce_kernel(const int* __restrict__ in,
                                                          int* __restrict__ bsum, int n) {
    int tid = threadIdx.x;
    int i = blockIdx.x * 256 + tid;
    int v = (i < n) ? in[i] : 0;
    int lane = tid & 63;
    int wave = tid >> 6;
#pragma unroll
    for (int off = 32; off > 0; off >>= 1) v += __shfl_down(v, off, 64);
    __shared__ int wsum[4];
    if (lane == 0) wsum[wave] = v;
    __syncthreads();
    if (tid == 0) bsum[blockIdx.x] = wsum[0] + wsum[1] + wsum[2] + wsum[3];
}

__global__ __launch_bounds__(256) void scan_bsum_kernel(int* __restrict__ bsum, int B) {
    int tid = threadIdx.x;
    int v = (tid < B) ? bsum[tid] : 0;
    int total;
    int excl = block_exscan256(v, tid, &total);
    if (tid < B) bsum[tid] = excl;
}

__global__ __launch_bounds__(256) void scan_apply_kernel(const int* __restrict__ in,
                                                         const int* __restrict__ bsum,
                                                         int* __restrict__ out, int n) {
    int tid = threadIdx.x;
    int i = blockIdx.x * 256 + tid;
    int v = (i < n) ? in[i] : 0;
    int total;
    int excl = block_exscan256(v, tid, &total);
    if (i < n) out[i] = bsum[blockIdx.x] + excl;
}

// ---- bucketed CSR build ----

__global__ __launch_bounds__(256) void bucket_count_kernel(const int* __restrict__ dst,
                                                           int* __restrict__ deg,
                                                           int* __restrict__ cnt) {
    __shared__ int lcnt[K_BUCK];
    int tid = threadIdx.x;
    for (int i = tid; i < K_BUCK; i += 256) lcnt[i] = 0;
    __syncthreads();
    int start = blockIdx.x * CHUNK;
    for (int it = tid; it < CHUNK; it += 256) {
        int d = dst[start + it];
        atomicAdd(&lcnt[d >> 8], 1);
        atomicAdd(&deg[d], 1);
    }
    __syncthreads();
    for (int i = tid; i < K_BUCK; i += 256) cnt[i * PART_B + blockIdx.x] = lcnt[i];
}

__global__ __launch_bounds__(256) void partition_kernel(const int* __restrict__ src,
                                                        const int* __restrict__ dst,
                                                        const int* __restrict__ base,
                                                        uint2* __restrict__ P) {
    __shared__ int lofs[K_BUCK];
    int tid = threadIdx.x;
    for (int i = tid; i < K_BUCK; i += 256) lofs[i] = base[i * PART_B + blockIdx.x];
    __syncthreads();
    int start = blockIdx.x * CHUNK;
    for (int it = tid; it < CHUNK; it += 256) {
        int e = start + it;
        int d = dst[e], s = src[e];
        int p = atomicAdd(&lofs[d >> 8], 1);
        P[p] = make_uint2((unsigned)d, (unsigned)s);
    }
}

__global__ __launch_bounds__(256) void fine_scatter_kernel(const uint2* __restrict__ P,
                                                           const int* __restrict__ base,
                                                           const int* __restrict__ deg,
                                                           int* __restrict__ rowptr,
                                                           int* __restrict__ col) {
    __shared__ int wloc[256];
    int b = blockIdx.x;
    int tid = threadIdx.x;
    int nbase = b << 8;
    int nn = min(256, N_NODES - nbase);
    int d = (tid < nn) ? deg[nbase + tid] : 0;
    int total;
    int excl = block_exscan256(d, tid, &total);
    int start = base[b * PART_B];
    int rp = start + excl;
    if (tid < nn) {
        rowptr[nbase + tid] = rp;
        wloc[tid] = rp;
    }
    if (b == K_BUCK - 1 && tid == 0) rowptr[N_NODES] = N_EDGES;
    __syncthreads();
    int end = (b + 1 < K_BUCK) ? base[(b + 1) * PART_B] : N_EDGES;
    for (int e = start + tid; e < end; e += 256) {
        uint2 pr = P[e];
        int rank = atomicAdd(&wloc[pr.x - nbase], 1);
        col[rank] = (int)pr.y;
    }
}

// Sort each row's neighbor list ascending by src. Optimization only: makes
// edge-index e correlate with src-quantile across the (fully resident) grid,
// so concurrent gathers sweep a narrow window of h -> L2 hit rate up.
// col is 3.2MB (L2-resident); insertion sort in place, one thread per row
// (avg deg 16 -> ~128 L2-cached accesses/row).
__global__ __launch_bounds__(256) void sort_rows_kernel(const int* __restrict__ rowptr,
                                                        int* __restrict__ col, int n) {
    int node = blockIdx.x * 256 + threadIdx.x;
    if (node >= n) return;
    int s = rowptr[node], e = rowptr[node + 1];
    for (int i = s + 1; i < e; ++i) {
        int key = col[i];
        int j = i - 1;
        while (j >= s && col[j] > key) {
            col[j + 1] = col[j];
            --j;
        }
        col[j + 1] = key;
    }
}

// ---------------- conversions ----------------

struct WT8 {
    const float* src[8];
    unsigned short* dst[8];
    int K[8];
    int N[8];
};

// W[K][N] fp32 -> Wt[N][K] bf16 (row-major transposed; for mfma_gemm2 LDS staging)
__global__ __launch_bounds__(256) void wtconv_kernel(WT8 p) {
    int wi = blockIdx.y;
    int K = p.K[wi], N = p.N[wi];
    int idx = blockIdx.x * 256 + threadIdx.x;
    if (idx >= K * N) return;
    int logn = 31 - __clz(N);
    int n = idx & (N - 1);
    int k = idx >> logn;
    p.dst[wi][(size_t)n * K + k] = f2bf(p.src[wi][idx]);
}

// W[K][N] fp32 -> Wp fragment-packed bf16: Wp[((t*S + s)*64 + lane)*8 + j]
//  = W[s*32 + (lane>>4)*8 + j][t*16 + (lane&15)]   (t = n-tile, s = k-tile)
__global__ __launch_bounds__(256) void wpconv_kernel(WT8 p) {
    int wi = blockIdx.y;
    int K = p.K[wi], N = p.N[wi];
    int idx = blockIdx.x * 256 + threadIdx.x;
    if (idx >= K * N) return;
    int S = K >> 5;
    int logs = 31 - __clz(S);
    int j = idx & 7;
    int l = (idx >> 3) & 63;
    int rest = idx >> 9;
    int s = rest & (S - 1);
    int t = rest >> logs;
    int k = s * 32 + ((l >> 4) << 3) + j;
    int n = t * 16 + (l & 15);
    p.dst[wi][idx] = f2bf(p.src[wi][(size_t)k * N + n]);
}

// ---------------- aggregation head (fused into GEMMs) ----------------

__device__ inline void acc8(uint4 v, float* a) {
    a[0] += bf2f(v.x & 0xFFFFu); a[1] += __uint_as_float(v.x & 0xFFFF0000u);
    a[2] += bf2f(v.y & 0xFFFFu); a[3] += __uint_as_float(v.y & 0xFFFF0000u);
    a[4] += bf2f(v.z & 0xFFFFu); a[5] += __uint_as_float(v.z & 0xFFFF0000u);
    a[6] += bf2f(v.w & 0xFFFFu); a[7] += __uint_as_float(v.w & 0xFFFF0000u);
}

// Aggregate BM rows (block tile) directly into the LDS A-tile As[r*(KIN+8)+k]
// (bf16). 8-deep edge pipelining (proven best; 16-deep spilled at the 64-reg
// tier, R7) + 4/2/1 remainder ladder; sequential-e accumulation order.
// Zero rows past M.
template <int BM, int KIN, bool RELU>
__device__ inline void agg_head(const unsigned short* __restrict__ h,
                                const int* __restrict__ rowptr,
                                const int* __restrict__ col,
                                const float* __restrict__ bias,
                                unsigned short* __restrict__ As,
                                int row0, int M, int tid) {
    constexpr int LPN = KIN / 8;       // uint4 lanes per row (16 @128, 8 @64)
    constexpr int GPS = 256 / LPN;     // node groups per sweep
    constexpr int NSW = BM / GPS;      // sweeps to cover BM rows
    constexpr int LDA = KIN + 8;
    const uint4* hv = (const uint4*)h;
    const int l = tid & (LPN - 1);
    const int g = tid / LPN;
#pragma unroll
    for (int sw = 0; sw < NSW; ++sw) {
        int r = sw * GPS + g;
        int node = row0 + r;
        uint4 o = make_uint4(0u, 0u, 0u, 0u);
        if (node < M) {
            float a[8] = {};
            uint4 vs = hv[(size_t)node * LPN + l];  // self (issued early)
            int s = rowptr[node], epos = rowptr[node + 1];
            int e = s;
            for (; e + 8 <= epos; e += 8) {
                int j0 = col[e],     j1 = col[e + 1], j2 = col[e + 2], j3 = col[e + 3];
                int j4 = col[e + 4], j5 = col[e + 5], j6 = col[e + 6], j7 = col[e + 7];
                uint4 v0 = hv[(size_t)j0 * LPN + l];
                uint4 v1 = hv[(size_t)j1 * LPN + l];
                uint4 v2 = hv[(size_t)j2 * LPN + l];
                uint4 v3 = hv[(size_t)j3 * LPN + l];
                uint4 v4 = hv[(size_t)j4 * LPN + l];
                uint4 v5 = hv[(size_t)j5 * LPN + l];
                uint4 v6 = hv[(size_t)j6 * LPN + l];
                uint4 v7 = hv[(size_t)j7 * LPN + l];
                acc8(v0, a); acc8(v1, a); acc8(v2, a); acc8(v3, a);
                acc8(v4, a); acc8(v5, a); acc8(v6, a); acc8(v7, a);
            }
            if (e + 4 <= epos) {
                int j0 = col[e], j1 = col[e + 1], j2 = col[e + 2], j3 = col[e + 3];
                uint4 v0 = hv[(size_t)j0 * LPN + l];
                uint4 v1 = hv[(size_t)j1 * LPN + l];
                uint4 v2 = hv[(size_t)j2 * LPN + l];
                uint4 v3 = hv[(size_t)j3 * LPN + l];
                acc8(v0, a); acc8(v1, a); acc8(v2, a); acc8(v3, a);
                e += 4;
            }
            if (e + 2 <= epos) {
                int j0 = col[e], j1 = col[e + 1];
                uint4 v0 = hv[(size_t)j0 * LPN + l];
                uint4 v1 = hv[(size_t)j1 * LPN + l];
                acc8(v0, a); acc8(v1, a);
                e += 2;
            }
            if (e < epos) acc8(hv[(size_t)col[e] * LPN + l], a);
            acc8(vs, a);
            if (RELU) {
                float4 b0 = *(const float4*)(bias + l * 8);
                float4 b1 = *(const float4*)(bias + l * 8 + 4);
                a[0] = fmaxf(a[0] + b0.x, 0.f); a[1] = fmaxf(a[1] + b0.y, 0.f);
                a[2] = fmaxf(a[2] + b0.z, 0.f); a[3] = fmaxf(a[3] + b0.w, 0.f);
                a[4] = fmaxf(a[4] + b1.x, 0.f); a[5] = fmaxf(a[5] + b1.y, 0.f);
                a[6] = fmaxf(a[6] + b1.z, 0.f); a[7] = fmaxf(a[7] + b1.w, 0.f);
            }
            o.x = (unsigned int)f2bf(a[0]) | ((unsigned int)f2bf(a[1]) << 16);
            o.y = (unsigned int)f2bf(a[2]) | ((unsigned int)f2bf(a[3]) << 16);
            o.z = (unsigned int)f2bf(a[4]) | ((unsigned int)f2bf(a[5]) << 16);
            o.w = (unsigned int)f2bf(a[6]) | ((unsigned int)f2bf(a[7]) << 16);
        }
        *(uint4*)(&As[r * LDA + l * 8]) = o;
    }
}

// ---------------- epilogue scale/shift helper ----------------

__device__ inline void epi_coeff(int mode, int c, const float* bias, const float* g,
                                 const float* be, const float* mu, const float* var,
                                 float* s, float* sh) {
    *s = 1.f; *sh = 0.f;
    if (mode == 0) {
        *sh = bias[c];
    } else if (mode == 1) {
        float t = g[c] * rsqrtf(var[c] + BN_EPS);
        *s = t;
        *sh = be[c] - mu[c] * t + bias[c] * t;
    }
}

// ---------------- bf16 MFMA GEMM v2 (LDS-B; used for L1 fp32-input GEMM) ----

template <int NT, bool F32A>
__global__ __launch_bounds__(256) void mfma_gemm2_kernel(
    const void* __restrict__ Ain, const unsigned short* __restrict__ Wt,
    unsigned short* __restrict__ C,
    int M, int K, int Nn, int mode, int gxblocks, int gy) {
    constexpr int BM = 128, BK = 64;
    constexpr int BN = NT * 16;
    constexpr int LDA = BK + 8;
    constexpr int LDB = BK + 8;
    constexpr int LDE = BN + 8;
    constexpr int NB_LD = (BN * BK / 8) / 256;
    __shared__ __align__(16) unsigned short smem[BM * LDA + BN * LDB];
    unsigned short* As = smem;
    unsigned short* Bs = smem + BM * LDA;
    unsigned short* Ep = smem;

    int id = blockIdx.x;
    int lo = id & 7;
    int t = id >> 3;
    int y = t % gy;
    int x = ((t / gy) << 3) | lo;
    if (x >= gxblocks) return;

    const int tid = threadIdx.x;
    const int wv = tid >> 6;
    const int ln = tid & 63;
    const int l15 = ln & 15;
    const int quad = ln >> 4;
    const int row0 = x * BM;
    const int col0 = y * BN;

    const unsigned short* A16 = (const unsigned short*)Ain;
    const float* A32 = (const float*)Ain;

    uint4 Ar[4], Br[NB_LD];

    auto loadA = [&](int k0) {
#pragma unroll
        for (int u = 0; u < 4; ++u) {
            int idx2 = tid + 256 * u;
            int r = idx2 >> 3, cg = (idx2 & 7) * 8;
            int gr = row0 + r;
            if (gr >= M) gr = M - 1;
            if (F32A) {
                float4 f0 = *(const float4*)(A32 + (size_t)gr * K + k0 + cg);
                float4 f1 = *(const float4*)(A32 + (size_t)gr * K + k0 + cg + 4);
                uint4 o;
                o.x = (unsigned)f2bf(f0.x) | ((unsigned)f2bf(f0.y) << 16);
                o.y = (unsigned)f2bf(f0.z) | ((unsigned)f2bf(f0.w) << 16);
                o.z = (unsigned)f2bf(f1.x) | ((unsigned)f2bf(f1.y) << 16);
                o.w = (unsigned)f2bf(f1.z) | ((unsigned)f2bf(f1.w) << 16);
                Ar[u] = o;
            } else {
                Ar[u] = *(const uint4*)(A16 + (size_t)gr * K + k0 + cg);
            }
        }
    };
    auto loadB = [&](int k0) {
#pragma unroll
        for (int u = 0; u < NB_LD; ++u) {
            int idx2 = tid + 256 * u;
            int r = idx2 >> 3, cg = (idx2 & 7) * 8;
            Br[u] = *(const uint4*)(Wt + (size_t)(col0 + r) * K + k0 + cg);
        }
    };
    auto stage = [&]() {
#pragma unroll
        for (int u = 0; u < 4; ++u) {
            int idx2 = tid + 256 * u;
            int r = idx2 >> 3, cg = (idx2 & 7) * 8;
            *(uint4*)(&As[r * LDA + cg]) = Ar[u];
        }
#pragma unroll
        for (int u = 0; u < NB_LD; ++u) {
            int idx2 = tid + 256 * u;
            int r = idx2 >> 3, cg = (idx2 & 7) * 8;
            *(uint4*)(&Bs[r * LDB + cg]) = Br[u];
        }
    };

    f32x4 acc[2][NT] = {};
    const int KT = K >> 6;
    loadA(0);
    loadB(0);
    for (int kt = 0; kt < KT; ++kt) {
        if (kt > 0) __syncthreads();
        stage();
        __syncthreads();
        if (kt + 1 < KT) {
            loadA((kt + 1) * 64);
            loadB((kt + 1) * 64);
        }
#pragma unroll
        for (int kh = 0; kh < 2; ++kh) {
            bshort8 af[2];
#pragma unroll
            for (int mt = 0; mt < 2; ++mt)
                af[mt] = *(const bshort8*)(&As[(wv * 32 + mt * 16 + l15) * LDA + kh * 32 + quad * 8]);
#pragma unroll
            for (int nt = 0; nt < NT; ++nt) {
                bshort8 bf = *(const bshort8*)(&Bs[(nt * 16 + l15) * LDB + kh * 32 + quad * 8]);
                acc[0][nt] = __builtin_amdgcn_mfma_f32_16x16x32_bf16(af[0], bf, acc[0][nt], 0, 0, 0);
                acc[1][nt] = __builtin_amdgcn_mfma_f32_16x16x32_bf16(af[1], bf, acc[1][nt], 0, 0, 0);
            }
        }
    }

    __syncthreads();
#pragma unroll
    for (int nt = 0; nt < NT; ++nt) {
#pragma unroll
        for (int mt = 0; mt < 2; ++mt) {
            int rl = wv * 32 + mt * 16 + quad * 4;
#pragma unroll
            for (int r = 0; r < 4; ++r) {
                float v = acc[mt][nt][r];
                if (mode != 2) v = fmaxf(v, 0.f);
                Ep[(rl + r) * LDE + nt * 16 + l15] = f2bf(v);
            }
        }
    }
    __syncthreads();
    constexpr int CGR = BN / 8;
    constexpr int NU = BM * CGR / 256;
#pragma unroll
    for (int u = 0; u < NU; ++u) {
        int idx2 = tid + 256 * u;
        int r = idx2 / CGR, cg = (idx2 % CGR) * 8;
        int grow = row0 + r;
        if (grow < M)
            *(uint4*)(C + (size_t)grow * Nn + col0 + cg) = *(const uint4*)(&Ep[r * LDE + cg]);
    }
}

// ---------------- fused agg + single GEMM (BM templated) ----------------
// C = epi( agg(h)+bias,relu  @ W ). No loadA/stage loop: agg_head fills As once.
// BM=64 proven best here (R8: BM=32 hurt the thin kernels).

template <int BM, int KIN, int DH, bool ARELU>
__global__ __launch_bounds__(256, 4) void agg_gemm_kernel(
    const unsigned short* __restrict__ h, const int* __restrict__ rowptr,
    const int* __restrict__ col, const float* __restrict__ abias,
    const unsigned short* __restrict__ Wp,
    int mode, const float* __restrict__ bias, const float* __restrict__ g,
    const float* __restrict__ be, const float* __restrict__ mu, const float* __restrict__ var,
    unsigned short* __restrict__ C, int M) {
    constexpr int MT = BM / 16;
    constexpr int LDA = KIN + 8;
    constexpr int LDE = DH + 8;
    constexpr int NT = DH / 64;
    constexpr int S = KIN / 32;
    constexpr int LMX = (LDA > LDE) ? LDA : LDE;
    __shared__ __align__(16) unsigned short smem[BM * LMX];
    unsigned short* As = smem;
    unsigned short* Ep = smem;

    const int tid = threadIdx.x;
    const int wv = tid >> 6;
    const int ln = tid & 63;
    const int l15 = ln & 15;
    const int quad = ln >> 4;
    const int tb = wv * NT;
    const int ch = wv * (DH / 4);
    const int row0 = blockIdx.x * BM;

    auto loadB = [&](int s, bshort8* d) {
#pragma unroll
        for (int nt = 0; nt < NT; ++nt)
            d[nt] = *(const bshort8*)(Wp + ((size_t)((tb + nt) * S + s) * 64 + ln) * 8);
    };

    bshort8 bf[NT], bnx[NT];
    loadB(0, bf);  // in flight under the gather phase (used right after; short live range)
    agg_head<BM, KIN, ARELU>(h, rowptr, col, abias, As, row0, M, tid);
    __syncthreads();

    f32x4 acc[MT][NT] = {};
#pragma unroll
    for (int ks = 0; ks < S; ++ks) {
        if (ks + 1 < S) loadB(ks + 1, bnx);
        bshort8 af[MT];
#pragma unroll
        for (int mt = 0; mt < MT; ++mt)
            af[mt] = *(const bshort8*)(&As[(mt * 16 + l15) * LDA + ks * 32 + quad * 8]);
#pragma unroll
        for (int nt = 0; nt < NT; ++nt)
#pragma unroll
            for (int mt = 0; mt < MT; ++mt)
                acc[mt][nt] = __builtin_amdgcn_mfma_f32_16x16x32_bf16(af[mt], bf[nt], acc[mt][nt], 0, 0, 0);
        if (ks + 1 < S) {
#pragma unroll
            for (int nt = 0; nt < NT; ++nt) bf[nt] = bnx[nt];
        }
    }
    __syncthreads();  // As dead; Ep overlay safe
#pragma unroll
    for (int nt = 0; nt < NT; ++nt) {
        int c = ch + nt * 16 + l15;
        float s, sh;
        epi_coeff(mode, c, bias, g, be, mu, var, &s, &sh);
#pragma unroll
        for (int mt = 0; mt < MT; ++mt) {
            int rl = mt * 16 + quad * 4;
#pragma unroll
            for (int r = 0; r < 4; ++r) {
                float v = acc[mt][nt][r] * s + sh;
                if (mode != 2) v = fmaxf(v, 0.f);
                Ep[(rl + r) * LDE + c] = f2bf(v);
            }
        }
    }
    __syncthreads();
    constexpr int CGR = DH / 8;
    constexpr int NU = BM * CGR / 256;
#pragma unroll
    for (int u = 0; u < NU; ++u) {
        int idx2 = tid + 256 * u;
        int r = idx2 / CGR, cg = (idx2 % CGR) * 8;
        int grow = row0 + r;
        if (grow < M)
            *(uint4*)(C + (size_t)grow * DH + cg) = *(const uint4*)(&Ep[r * LDE + cg]);
    }
}

// ---------------- fused agg + 2-stage MLP (BM templated) ----------------
// C = epi2( epi1( (agg(h)[+bias,relu]) @ W1 ) @ W2 ). As/T1/Ep overlay.
// BM=64 for the thin <128,128,64> instance (R8: 32 hurt it).
// bf2 loaded late (short live range, R6).

template <int BM, int KIN, int DH1, int DH2, bool ARELU>
__global__ __launch_bounds__(256, 4) void agg_mlp_kernel(
    const unsigned short* __restrict__ h, const int* __restrict__ rowptr,
    const int* __restrict__ col, const float* __restrict__ abias,
    const unsigned short* __restrict__ Wp1, const unsigned short* __restrict__ Wp2,
    int mode1, const float* __restrict__ b1, const float* __restrict__ g1,
    const float* __restrict__ be1, const float* __restrict__ mu1, const float* __restrict__ var1,
    int mode2, const float* __restrict__ b2, const float* __restrict__ g2,
    const float* __restrict__ be2, const float* __restrict__ mu2, const float* __restrict__ var2,
    unsigned short* __restrict__ C, int M) {
    constexpr int MT = BM / 16;
    constexpr int LDA = KIN + 8;
    constexpr int LT1 = DH1 + 8;
    constexpr int LDE = DH2 + 8;
    constexpr int NT1 = DH1 / 64;
    constexpr int NT2 = DH2 / 64;
    constexpr int S1 = KIN / 32;
    constexpr int S2 = DH1 / 32;
    constexpr int LM0 = (LDA > LT1) ? LDA : LT1;
    constexpr int LMX = (LM0 > LDE) ? LM0 : LDE;
    __shared__ __align__(16) unsigned short smem[BM * LMX];
    unsigned short* As = smem;
    unsigned short* T1 = smem;

    const int tid = threadIdx.x;
    const int wv = tid >> 6;
    const int ln = tid & 63;
    const int l15 = ln & 15;
    const int quad = ln >> 4;
    const int tb1 = wv * NT1;
    const int tb2 = wv * NT2;
    const int ch1 = wv * (DH1 / 4);
    const int ch2 = wv * (DH2 / 4);
    const int row0 = blockIdx.x * BM;

    auto loadB1 = [&](int s, bshort8* d) {
#pragma unroll
        for (int nt = 0; nt < NT1; ++nt)
            d[nt] = *(const bshort8*)(Wp1 + ((size_t)((tb1 + nt) * S1 + s) * 64 + ln) * 8);
    };
    auto loadB2 = [&](int s, bshort8* d) {
#pragma unroll
        for (int nt = 0; nt < NT2; ++nt)
            d[nt] = *(const bshort8*)(Wp2 + ((size_t)((tb2 + nt) * S2 + s) * 64 + ln) * 8);
    };

    bshort8 bf[NT1], bnx[NT1], bf2[NT2];
    loadB1(0, bf);
    agg_head<BM, KIN, ARELU>(h, rowptr, col, abias, As, row0, M, tid);
    __syncthreads();

    // ---- stage 1: A from As (LDS-resident, no restaging) ----
    f32x4 acc1[MT][NT1] = {};
#pragma unroll
    for (int ks = 0; ks < S1; ++ks) {
        if (ks + 1 < S1) loadB1(ks + 1, bnx);
        bshort8 af[MT];
#pragma unroll
        for (int mt = 0; mt < MT; ++mt)
            af[mt] = *(const bshort8*)(&As[(mt * 16 + l15) * LDA + ks * 32 + quad * 8]);
#pragma unroll
        for (int nt = 0; nt < NT1; ++nt)
#pragma unroll
            for (int mt = 0; mt < MT; ++mt)
                acc1[mt][nt] = __builtin_amdgcn_mfma_f32_16x16x32_bf16(af[mt], bf[nt], acc1[mt][nt], 0, 0, 0);
        if (ks + 1 < S1) {
#pragma unroll
            for (int nt = 0; nt < NT1; ++nt) bf[nt] = bnx[nt];
        }
    }
    __syncthreads();  // As dead; T1 overlay safe
    // epi1 -> T1 (LDS)
#pragma unroll
    for (int nt = 0; nt < NT1; ++nt) {
        int c = ch1 + nt * 16 + l15;
        float s, sh;
        epi_coeff(mode1, c, b1, g1, be1, mu1, var1, &s, &sh);
#pragma unroll
        for (int mt = 0; mt < MT; ++mt) {
            int rl = mt * 16 + quad * 4;
#pragma unroll
            for (int r = 0; r < 4; ++r) {
                float v = acc1[mt][nt][r] * s + sh;
                if (mode1 != 2) v = fmaxf(v, 0.f);
                T1[(rl + r) * LT1 + c] = f2bf(v);
            }
        }
    }
    loadB2(0, bf2);  // issue stage-2 B0 load; latency hides under the barrier + epi drain
    __syncthreads();

    // ---- stage 2: A from T1 (LDS), B depth-1 pipelined, barrier-free loop ----
    f32x4 acc2[MT][NT2] = {};
    bshort8 bnx2[NT2];
#pragma unroll
    for (int ks = 0; ks < S2; ++ks) {
        if (ks + 1 < S2) loadB2(ks + 1, bnx2);
        bshort8 af[MT];
#pragma unroll
        for (int mt = 0; mt < MT; ++mt)
            af[mt] = *(const bshort8*)(&T1[(mt * 16 + l15) * LT1 + ks * 32 + quad * 8]);
#pragma unroll
        for (int nt = 0; nt < NT2; ++nt)
#pragma unroll
            for (int mt = 0; mt < MT; ++mt)
                acc2[mt][nt] = __builtin_amdgcn_mfma_f32_16x16x32_bf16(af[mt], bf2[nt], acc2[mt][nt], 0, 0, 0);
        if (ks + 1 < S2) {
#pragma unroll
            for (int nt = 0; nt < NT2; ++nt) bf2[nt] = bnx2[nt];
        }
    }
    __syncthreads();  // T1 dead; Ep overlay safe

    unsigned short* Ep = T1;
#pragma unroll
    for (int nt = 0; nt < NT2; ++nt) {
        int c = ch2 + nt * 16 + l15;
        float s, sh;
        epi_coeff(mode2, c, b2, g2, be2, mu2, var2, &s, &sh);
#pragma unroll
        for (int mt = 0; mt < MT; ++mt) {
            int rl = mt * 16 + quad * 4;
#pragma unroll
            for (int r = 0; r < 4; ++r) {
                float v = acc2[mt][nt][r] * s + sh;
                if (mode2 != 2) v = fmaxf(v, 0.f);
                Ep[(rl + r) * LDE + c] = f2bf(v);
            }
        }
    }
    __syncthreads();
    constexpr int CGR = DH2 / 8;
    constexpr int NU = BM * CGR / 256;
#pragma unroll
    for (int u = 0; u < NU; ++u) {
        int idx2 = tid + 256 * u;
        int r = idx2 / CGR, cg = (idx2 % CGR) * 8;
        int grow = row0 + r;
        if (grow < M)
            *(uint4*)(C + (size_t)grow * DH2 + cg) = *(const uint4*)(&Ep[r * LDE + cg]);
    }
}

// ---------------- fused agg + 3-stage MLP (L2 + L3-G1 folded) ----------------
// C = W3( epi2( epi1( (agg(h)) @ W1 ) @ W2 ) )  [mode3=2 raw].
// Exploits agg(h)@W = agg(h@W) linearity downstream: h2 never hits global.
// As/T1/T2/Ep all overlay one buffer (barrier-separated). R10: 60 VGPR,
// no spill, WRITE 12.5MB, -10us total.

template <int BM, int KIN, int DH1, int DH2, int DH3, bool ARELU>
__global__ __launch_bounds__(256, 4) void agg_mlp3_kernel(
    const unsigned short* __restrict__ h, const int* __restrict__ rowptr,
    const int* __restrict__ col, const float* __restrict__ abias,
    const unsigned short* __restrict__ Wp1, const unsigned short* __restrict__ Wp2,
    const unsigned short* __restrict__ Wp3,
    int mode1, const float* __restrict__ b1, const float* __restrict__ g1,
    const float* __restrict__ be1, const float* __restrict__ mu1, const float* __restrict__ var1,
    int mode2, const float* __restrict__ b2, const float* __restrict__ g2,
    const float* __restrict__ be2, const float* __restrict__ mu2, const float* __restrict__ var2,
    unsigned short* __restrict__ C, int M) {
    constexpr int MT = BM / 16;
    constexpr int LDA = KIN + 8;
    constexpr int LT1 = DH1 + 8;
    constexpr int LT2 = DH2 + 8;
    constexpr int LDE = DH3 + 8;
    constexpr int NT1 = DH1 / 64;
    constexpr int NT2 = DH2 / 64;
    constexpr int NT3 = DH3 / 64;
    constexpr int S1 = KIN / 32;
    constexpr int S2 = DH1 / 32;
    constexpr int S3 = DH2 / 32;
    constexpr int LM0 = (LDA > LT1) ? LDA : LT1;
    constexpr int LM1 = (LM0 > LT2) ? LM0 : LT2;
    constexpr int LMX = (LM1 > LDE) ? LM1 : LDE;
    __shared__ __align__(16) unsigned short smem[BM * LMX];
    unsigned short* As = smem;
    unsigned short* T1 = smem;
    unsigned short* T2 = smem;

    const int tid = threadIdx.x;
    const int wv = tid >> 6;
    const int ln = tid & 63;
    const int l15 = ln & 15;
    const int quad = ln >> 4;
    const int tb1 = wv * NT1;
    const int tb2 = wv * NT2;
    const int tb3 = wv * NT3;
    const int ch1 = wv * (DH1 / 4);
    const int ch2 = wv * (DH2 / 4);
    const int ch3 = wv * (DH3 / 4);
    const int row0 = blockIdx.x * BM;

    auto loadB1 = [&](int s, bshort8* d) {
#pragma unroll
        for (int nt = 0; nt < NT1; ++nt)
            d[nt] = *(const bshort8*)(Wp1 + ((size_t)((tb1 + nt) * S1 + s) * 64 + ln) * 8);
    };
    auto loadB2 = [&](int s, bshort8* d) {
#pragma unroll
        for (int nt = 0; nt < NT2; ++nt)
            d[nt] = *(const bshort8*)(Wp2 + ((size_t)((tb2 + nt) * S2 + s) * 64 + ln) * 8);
    };
    auto loadB3 = [&](int s, bshort8* d) {
#pragma unroll
        for (int nt = 0; nt < NT3; ++nt)
            d[nt] = *(const bshort8*)(Wp3 + ((size_t)((tb3 + nt) * S3 + s) * 64 + ln) * 8);
    };

    bshort8 bf[NT1], bnx[NT1];
    loadB1(0, bf);
    agg_head<BM, KIN, ARELU>(h, rowptr, col, abias, As, row0, M, tid);
    __syncthreads();

    // ---- stage 1: A = As (agg output) ----
    f32x4 acc1[MT][NT1] = {};
#pragma unroll
    for (int ks = 0; ks < S1; ++ks) {
        if (ks + 1 < S1) loadB1(ks + 1, bnx);
        bshort8 af[MT];
#pragma unroll
        for (int mt = 0; mt < MT; ++mt)
            af[mt] = *(const bshort8*)(&As[(mt * 16 + l15) * LDA + ks * 32 + quad * 8]);
#pragma unroll
        for (int nt = 0; nt < NT1; ++nt)
#pragma unroll
            for (int mt = 0; mt < MT; ++mt)
                acc1[mt][nt] = __builtin_amdgcn_mfma_f32_16x16x32_bf16(af[mt], bf[nt], acc1[mt][nt], 0, 0, 0);
        if (ks + 1 < S1) {
#pragma unroll
            for (int nt = 0; nt < NT1; ++nt) bf[nt] = bnx[nt];
        }
    }
    __syncthreads();  // As dead; T1 overlay safe
#pragma unroll
    for (int nt = 0; nt < NT1; ++nt) {
        int c = ch1 + nt * 16 + l15;
        float s, sh;
        epi_coeff(mode1, c, b1, g1, be1, mu1, var1, &s, &sh);
#pragma unroll
        for (int mt = 0; mt < MT; ++mt) {
            int rl = mt * 16 + quad * 4;
#pragma unroll
            for (int r = 0; r < 4; ++r) {
                float v = acc1[mt][nt][r] * s + sh;
                if (mode1 != 2) v = fmaxf(v, 0.f);
                T1[(rl + r) * LT1 + c] = f2bf(v);
            }
        }
    }
    bshort8 bf2[NT2], bnx2[NT2];
    loadB2(0, bf2);  // latency hides under the barrier
    __syncthreads();

    // ---- stage 2: A = T1 ----
    f32x4 acc2[MT][NT2] = {};
#pragma unroll
    for (int ks = 0; ks < S2; ++ks) {
        if (ks + 1 < S2) loadB2(ks + 1, bnx2);
        bshort8 af[MT];
#pragma unroll
        for (int mt = 0; mt < MT; ++mt)
            af[mt] = *(const bshort8*)(&T1[(mt * 16 + l15) * LT1 + ks * 32 + quad * 8]);
#pragma unroll
        for (int nt = 0; nt < NT2; ++nt)
#pragma unroll
            for (int mt = 0; mt < MT; ++mt)
                acc2[mt][nt] = __builtin_amdgcn_mfma_f32_16x16x32_bf16(af[mt], bf2[nt], acc2[mt][nt], 0, 0, 0);
        if (ks + 1 < S2) {
#pragma unroll
            for (int nt = 0; nt < NT2; ++nt) bf2[nt] = bnx2[nt];
        }
    }
    __syncthreads();  // T1 dead; T2 overlay safe
#pragma unroll
    for (int nt = 0; nt < NT2; ++nt) {
        int c = ch2 + nt * 16 + l15;
        float s, sh;
        epi_coeff(mode2, c, b2, g2, be2, mu2, var2, &s, &sh);
#pragma unroll
        for (int mt = 0; mt < MT; ++mt) {
            int rl = mt * 16 + quad * 4;
#pragma unroll
            for (int r = 0; r < 4; ++r) {
                float v = acc2[mt][nt][r] * s + sh;
                if (mode2 != 2) v = fmaxf(v, 0.f);
                T2[(rl + r) * LT2 + c] = f2bf(v);
            }
        }
    }
    bshort8 bf3[NT3], bnx3[NT3];
    loadB3(0, bf3);
    __syncthreads();

    // ---- stage 3: A = T2, raw output (mode 2) ----
    f32x4 acc3[MT][NT3] = {};
#pragma unroll
    for (int ks = 0; ks < S3; ++ks) {
        if (ks + 1 < S3) loadB3(ks + 1, bnx3);
        bshort8 af[MT];
#pragma unroll
        for (int mt = 0; mt < MT; ++mt)
            af[mt] = *(const bshort8*)(&T2[(mt * 16 + l15) * LT2 + ks * 32 + quad * 8]);
#pragma unroll
        for (int nt = 0; nt < NT3; ++nt)
#pragma unroll
            for (int mt = 0; mt < MT; ++mt)
                acc3[mt][nt] = __builtin_amdgcn_mfma_f32_16x16x32_bf16(af[mt], bf3[nt], acc3[mt][nt], 0, 0, 0);
        if (ks + 1 < S3) {
#pragma unroll
            for (int nt = 0; nt < NT3; ++nt) bf3[nt] = bnx3[nt];
        }
    }
    __syncthreads();  // T2 dead; Ep overlay safe

    unsigned short* Ep = smem;
#pragma unroll
    for (int nt = 0; nt < NT3; ++nt) {
        int c = ch3 + nt * 16 + l15;
#pragma unroll
        for (int mt = 0; mt < MT; ++mt) {
            int rl = mt * 16 + quad * 4;
#pragma unroll
            for (int r = 0; r < 4; ++r)
                Ep[(rl + r) * LDE + c] = f2bf(acc3[mt][nt][r]);  // raw
        }
    }
    __syncthreads();
    constexpr int CGR = DH3 / 8;
    constexpr int NU = BM * CGR / 256;
#pragma unroll
    for (int u = 0; u < NU; ++u) {
        int idx2 = tid + 256 * u;
        int r = idx2 / CGR, cg = (idx2 % CGR) * 8;
        int grow = row0 + r;
        if (grow < M)
            *(uint4*)(C + (size_t)grow * DH3 + cg) = *(const uint4*)(&Ep[r * LDE + cg]);
    }
}

// ---------------- fused agg + GEMM + classifier (L4 tail, BM=64) ----------------
// out = epi_bn( (relu(agg(h)+b4a)) @ W ) @ wc + bc.  KIN=DH=64.

__global__ __launch_bounds__(256, 4) void agg_cls_kernel(
    const unsigned short* __restrict__ h, const int* __restrict__ rowptr,
    const int* __restrict__ col, const float* __restrict__ abias,
    const unsigned short* __restrict__ Wp,
    const float* __restrict__ bias, const float* __restrict__ g,
    const float* __restrict__ be, const float* __restrict__ mu, const float* __restrict__ var,
    const float* __restrict__ wcls, const float* __restrict__ bcls,
    float* __restrict__ outp, int M) {
    constexpr int BM = 64, KIN = 64, DH = 64;
    constexpr int LDA = KIN + 8;
    constexpr int LDE = DH + 8;
    constexpr int NT = 1;
    constexpr int S = KIN / 32;
    __shared__ __align__(16) unsigned short smem[BM * LDA];
    unsigned short* As = smem;
    unsigned short* Ep = smem;

    const int tid = threadIdx.x;
    const int wv = tid >> 6;
    const int ln = tid & 63;
    const int l15 = ln & 15;
    const int quad = ln >> 4;
    const int tb = wv;              // NT=1
    const int ch = wv * 16;
    const int row0 = blockIdx.x * BM;

    auto loadB = [&](int s, bshort8* d) {
        d[0] = *(const bshort8*)(Wp + ((size_t)(tb * S + s) * 64 + ln) * 8);
    };

    bshort8 bf[NT], bnx[NT];
    loadB(0, bf);
    agg_head<BM, KIN, true>(h, rowptr, col, abias, As, row0, M, tid);
    __syncthreads();

    f32x4 acc[4][NT] = {};
#pragma unroll
    for (int ks = 0; ks < S; ++ks) {
        if (ks + 1 < S) loadB(ks + 1, bnx);
        bshort8 af[4];
#pragma unroll
        for (int mt = 0; mt < 4; ++mt)
            af[mt] = *(const bshort8*)(&As[(mt * 16 + l15) * LDA + ks * 32 + quad * 8]);
#pragma unroll
        for (int mt = 0; mt < 4; ++mt)
            acc[mt][0] = __builtin_amdgcn_mfma_f32_16x16x32_bf16(af[mt], bf[0], acc[mt][0], 0, 0, 0);
        if (ks + 1 < S) bf[0] = bnx[0];
    }
    __syncthreads();  // As dead; Ep overlay safe
    {
        int c = ch + l15;
        float s, sh;
        epi_coeff(1, c, bias, g, be, mu, var, &s, &sh);
#pragma unroll
        for (int mt = 0; mt < 4; ++mt) {
            int rl = mt * 16 + quad * 4;
#pragma unroll
            for (int r = 0; r < 4; ++r) {
                float v = fmaxf(acc[mt][0][r] * s + sh, 0.f);
                Ep[(rl + r) * LDE + c] = f2bf(v);
            }
        }
    }
    __syncthreads();
    if (tid < 128) {
        int r = tid >> 1, j = tid & 1;
        int grow = row0 + r;
        if (grow < M) {
            float s = 0.f;
#pragma unroll 8
            for (int k = 0; k < 64; ++k)
                s += bf2f(Ep[r * LDE + k]) * wcls[k * 2 + j];
            outp[(size_t)grow * 2 + j] = s + bcls[j];
        }
    }
}

// ---------------- launch ----------------

extern "C" void kernel_launch(void* const* d_in, const int* in_sizes, int n_in,
                              void* d_out, int out_size, void* d_ws, size_t ws_size,
                              hipStream_t stream) {
    const float* x = (const float*)d_in[0];
    const int* ei = (const int*)d_in[1];
    const int* src = ei;
    const int* dst = ei + N_EDGES;
    const float* w[4][2];
    const float* b[4][2];
    const float* bng[4];
    const float* bnb[4];
    const float* bnm[4];
    const float* bnv[4];
    int idx = 2;
    for (int i = 0; i < 4; ++i) {
        w[i][0] = (const float*)d_in[idx++];
        b[i][0] = (const float*)d_in[idx++];
        w[i][1] = (const float*)d_in[idx++];
        b[i][1] = (const float*)d_in[idx++];
        bng[i] = (const float*)d_in[idx++];
        bnb[i] = (const float*)d_in[idx++];
        bnm[i] = (const float*)d_in[idx++];
        bnv[i] = (const float*)d_in[idx++];
    }
    const float* wc = (const float*)d_in[idx++];
    const float* bc = (const float*)d_in[idx++];
    float* out = (float*)d_out;

    char* ws = (char*)d_ws;
    size_t off = 0;
    auto alloc = [&](size_t bytes) {
        char* p = ws + off;
        off = (off + bytes + 255) & ~(size_t)255;
        return p;
    };
    int* deg = (int*)alloc((size_t)N_NODES * 4);
    int* rowptr = (int*)alloc((size_t)(N_NODES + 1) * 4);
    int* cnt = (int*)alloc((size_t)K_BUCK * PART_B * 4);
    int* bsum2 = (int*)alloc((size_t)K_BUCK * 4);
    int* col = (int*)alloc((size_t)N_EDGES * 4 + 64);   // +64B pad: 8-wide col reads may touch past row end
    uint2* P = (uint2*)alloc((size_t)N_EDGES * 8);
    unsigned short* bufA = (unsigned short*)alloc((size_t)N_NODES * 256 * 2);
    unsigned short* bufB = (unsigned short*)alloc((size_t)N_NODES * 256 * 2);
    unsigned short* bufC = (unsigned short*)alloc((size_t)N_NODES * 256 * 2);
    const int dims_in[4] = {256, 128, 256, 128};
    const int dims_h[4] = {128, 256, 128, 64};
    unsigned short* wt[4][2];
    unsigned short* wp[4][2];
    for (int L = 0; L < 4; ++L) {
        wt[L][0] = (unsigned short*)alloc((size_t)dims_in[L] * dims_h[L] * 2);
        wt[L][1] = (unsigned short*)alloc((size_t)dims_h[L] * dims_h[L] * 2);
        wp[L][0] = (unsigned short*)alloc((size_t)dims_in[L] * dims_h[L] * 2);
        wp[L][1] = (unsigned short*)alloc((size_t)dims_h[L] * dims_h[L] * 2);
    }
    (void)ws_size;

    // weight conversions: row-major transposed (wt) + fragment-packed (wp)
    WT8 p;
    for (int L = 0; L < 4; ++L) {
        p.src[L * 2] = w[L][0];     p.dst[L * 2] = wt[L][0];
        p.K[L * 2] = dims_in[L];    p.N[L * 2] = dims_h[L];
        p.src[L * 2 + 1] = w[L][1]; p.dst[L * 2 + 1] = wt[L][1];
        p.K[L * 2 + 1] = dims_h[L]; p.N[L * 2 + 1] = dims_h[L];
    }
    wtconv_kernel<<<dim3(256, 8), 256, 0, stream>>>(p);
    WT8 q = p;
    for (int L = 0; L < 4; ++L) {
        q.dst[L * 2] = wp[L][0];
        q.dst[L * 2 + 1] = wp[L][1];
    }
    wpconv_kernel<<<dim3(256, 8), 256, 0, stream>>>(q);

    // ---- CSR build ----
    hipMemsetAsync(deg, 0, (size_t)N_NODES * 4, stream);
    bucket_count_kernel<<<PART_B, 256, 0, stream>>>(dst, deg, cnt);
    scan_reduce_kernel<<<K_BUCK, 256, 0, stream>>>(cnt, bsum2, K_BUCK * PART_B);
    scan_bsum_kernel<<<1, 256, 0, stream>>>(bsum2, K_BUCK);
    scan_apply_kernel<<<K_BUCK, 256, 0, stream>>>(cnt, bsum2, cnt, K_BUCK * PART_B);
    partition_kernel<<<PART_B, 256, 0, stream>>>(src, dst, cnt, P);
    fine_scatter_kernel<<<K_BUCK, 256, 0, stream>>>(P, cnt, deg, rowptr, col);
    // sort each row's neighbors by src: concurrent gathers then sweep h in
    // quantile order -> L2 hit rate up (gather is latency-bound on misses)
    sort_rows_kernel<<<(N_NODES + 255) / 256, 256, 0, stream>>>(rowptr, col, N_NODES);

    const int gx = (N_NODES + 127) / 128;       // 391
    const int gxp = ((gx + 7) / 8) * 8;         // 392
    const int gx32 = (N_NODES + 31) / 32;       // 1563
    const int gx64 = (N_NODES + 63) / 64;       // 782
    const int M = N_NODES;

    // ---- L1-G1: x @ w1a (fp32 A, 256->128, raw) -> bufA ----
    mfma_gemm2_kernel<8, true><<<gxp, 256, 0, stream>>>(
        x, wt[0][0], bufA, M, 256, 128, 2, gx, 1);

    // ---- L1: [agg(bufA)+b1a,relu] @ w1b -> BN+relu -> bufC (h1) ----
    agg_gemm_kernel<64, 128, 128, true><<<gx64, 256, 0, stream>>>(
        bufA, rowptr, col, b[0][0], wp[0][1],
        1, b[0][1], bng[0], bnb[0], bnm[0], bnv[0], bufC, M);

    // ---- L2 + L3-G1 fused: [agg(bufC)] @ w2a+b2a relu @ w2b BN relu @ w3a raw -> bufA ----
    agg_mlp3_kernel<32, 128, 256, 256, 128, false><<<gx32, 256, 0, stream>>>(
        bufC, rowptr, col, nullptr, wp[1][0], wp[1][1], wp[2][0],
        0, b[1][0], nullptr, nullptr, nullptr, nullptr,
        1, b[1][1], bng[1], bnb[1], bnm[1], bnv[1],
        bufA, M);

    // ---- L3/L4: [agg(bufA)+b3a,relu] @ w3b BN+relu -> @ w4a raw -> bufB ----
    agg_mlp_kernel<64, 128, 128, 64, true><<<gx64, 256, 0, stream>>>(
        bufA, rowptr, col, b[2][0], wp[2][1], wp[3][0],
        1, b[2][1], bng[2], bnb[2], bnm[2], bnv[2],
        2, nullptr, nullptr, nullptr, nullptr, nullptr,
        bufB, M);

    // ---- L4 tail: [agg(bufB)+b4a,relu] @ w4b BN+relu -> classifier -> out ----
    agg_cls_kernel<<<gx64, 256, 0, stream>>>(
        bufB, rowptr, col, b[3][0], wp[3][1],
        b[3][1], bng[3], bnb[3], bnm[3], bnv[3], wc, bc, out, M);
}

// Round 12
// 380.334 us; speedup vs baseline: 1.2300x; 1.2300x over previous
//
#include <hip/hip_runtime.h>

#define N_NODES 50000
#define N_EDGES 800000
#define BN_EPS 1e-5f
#define K_BUCK 196        // dst >> 8 buckets (256 nodes each)
#define PART_B 256        // partition blocks
#define CHUNK 3125        // N_EDGES / PART_B

typedef __attribute__((ext_vector_type(8))) short bshort8;
typedef __attribute__((ext_vector_type(4))) float f32x4;

__device__ inline float bf2f(unsigned int u16) {
    return __uint_as_float(u16 << 16);
}
__device__ inline unsigned short f2bf(float f) {
    unsigned int u = __float_as_uint(f);
    u = (u + 0x7FFFu + ((u >> 16) & 1u)) >> 16;
    return (unsigned short)u;
}

// ---------------- scan helpers ----------------

__device__ inline int block_exscan256(int v, int tid, int* total) {
    int lane = tid & 63;
    int wave = tid >> 6;
    int incl = v;
#pragma unroll
    for (int off = 1; off < 64; off <<= 1) {
        int t = __shfl_up(incl, off, 64);
        if (lane >= off) incl += t;
    }
    __shared__ int wsum[4];
    if (lane == 63) wsum[wave] = incl;
    __syncthreads();
    int w0 = wsum[0], w1 = wsum[1], w2 = wsum[2], w3 = wsum[3];
    __syncthreads();
    int wofs = (wave > 0 ? w0 : 0) + (wave > 1 ? w1 : 0) + (wave > 2 ? w2 : 0);
    *total = w0 + w1 + w2 + w3;
    return wofs + incl - v;
}

__global__ __launch_bounds__(256) void scan_reduce_kernel(const int* __restrict__ in,
                                                          int* __restrict__ bsum, int n) {
    int tid = threadIdx.x;
    int i = blockIdx.x * 256 + tid;
    int v = (i < n) ? in[i] : 0;
    int lane = tid & 63;
    int wave = tid >> 6;
#pragma unroll
    for (int off = 32; off > 0; off >>= 1) v += __shfl_down(v, off, 64);
    __shared__ int wsum[4];
    if (lane == 0) wsum[wave] = v;
    __syncthreads();
    if (tid == 0) bsum[blockIdx.x] = wsum[0] + wsum[1] + wsum[2] + wsum[3];
}

__global__ __launch_bounds__(256) void scan_bsum_kernel(int* __restrict__ bsum, int B) {
    int tid = threadIdx.x;
    int v = (tid < B) ? bsum[tid] : 0;
    int total;
    int excl = block_exscan256(v, tid, &total);
    if (tid < B) bsum[tid] = excl;
}

__global__ __launch_bounds__(256) void scan_apply_kernel(const int* __restrict__ in,
                                                         const int* __restrict__ bsum,
                                                         int* __restrict__ out, int n) {
    int tid = threadIdx.x;
    int i = blockIdx.x * 256 + tid;
    int v = (i < n) ? in[i] : 0;
    int total;
    int excl = block_exscan256(v, tid, &total);
    if (i < n) out[i] = bsum[blockIdx.x] + excl;
}

// ---- bucketed CSR build ----

__global__ __launch_bounds__(256) void bucket_count_kernel(const int* __restrict__ dst,
                                                           int* __restrict__ deg,
                                                           int* __restrict__ cnt) {
    __shared__ int lcnt[K_BUCK];
    int tid = threadIdx.x;
    for (int i = tid; i < K_BUCK; i += 256) lcnt[i] = 0;
    __syncthreads();
    int start = blockIdx.x * CHUNK;
    for (int it = tid; it < CHUNK; it += 256) {
        int d = dst[start + it];
        atomicAdd(&lcnt[d >> 8], 1);
        atomicAdd(&deg[d], 1);
    }
    __syncthreads();
    for (int i = tid; i < K_BUCK; i += 256) cnt[i * PART_B + blockIdx.x] = lcnt[i];
}

__global__ __launch_bounds__(256) void partition_kernel(const int* __restrict__ src,
                                                        const int* __restrict__ dst,
                                                        const int* __restrict__ base,
                                                        uint2* __restrict__ P) {
    __shared__ int lofs[K_BUCK];
    int tid = threadIdx.x;
    for (int i = tid; i < K_BUCK; i += 256) lofs[i] = base[i * PART_B + blockIdx.x];
    __syncthreads();
    int start = blockIdx.x * CHUNK;
    for (int it = tid; it < CHUNK; it += 256) {
        int e = start + it;
        int d = dst[e], s = src[e];
        int p = atomicAdd(&lofs[d >> 8], 1);
        P[p] = make_uint2((unsigned)d, (unsigned)s);
    }
}

__global__ __launch_bounds__(256) void fine_scatter_kernel(const uint2* __restrict__ P,
                                                           const int* __restrict__ base,
                                                           const int* __restrict__ deg,
                                                           int* __restrict__ rowptr,
                                                           int* __restrict__ col) {
    __shared__ int wloc[256];
    int b = blockIdx.x;
    int tid = threadIdx.x;
    int nbase = b << 8;
    int nn = min(256, N_NODES - nbase);
    int d = (tid < nn) ? deg[nbase + tid] : 0;
    int total;
    int excl = block_exscan256(d, tid, &total);
    int start = base[b * PART_B];
    int rp = start + excl;
    if (tid < nn) {
        rowptr[nbase + tid] = rp;
        wloc[tid] = rp;
    }
    if (b == K_BUCK - 1 && tid == 0) rowptr[N_NODES] = N_EDGES;
    __syncthreads();
    int end = (b + 1 < K_BUCK) ? base[(b + 1) * PART_B] : N_EDGES;
    for (int e = start + tid; e < end; e += 256) {
        uint2 pr = P[e];
        int rank = atomicAdd(&wloc[pr.x - nbase], 1);
        col[rank] = (int)pr.y;
    }
}

// ---------------- conversions ----------------

struct WT8 {
    const float* src[8];
    unsigned short* dst[8];
    int K[8];
    int N[8];
};

// W[K][N] fp32 -> Wt[N][K] bf16 (row-major transposed; for mfma_gemm2 LDS staging)
__global__ __launch_bounds__(256) void wtconv_kernel(WT8 p) {
    int wi = blockIdx.y;
    int K = p.K[wi], N = p.N[wi];
    int idx = blockIdx.x * 256 + threadIdx.x;
    if (idx >= K * N) return;
    int logn = 31 - __clz(N);
    int n = idx & (N - 1);
    int k = idx >> logn;
    p.dst[wi][(size_t)n * K + k] = f2bf(p.src[wi][idx]);
}

// W[K][N] fp32 -> Wp fragment-packed bf16: Wp[((t*S + s)*64 + lane)*8 + j]
//  = W[s*32 + (lane>>4)*8 + j][t*16 + (lane&15)]   (t = n-tile, s = k-tile)
__global__ __launch_bounds__(256) void wpconv_kernel(WT8 p) {
    int wi = blockIdx.y;
    int K = p.K[wi], N = p.N[wi];
    int idx = blockIdx.x * 256 + threadIdx.x;
    if (idx >= K * N) return;
    int S = K >> 5;
    int logs = 31 - __clz(S);
    int j = idx & 7;
    int l = (idx >> 3) & 63;
    int rest = idx >> 9;
    int s = rest & (S - 1);
    int t = rest >> logs;
    int k = s * 32 + ((l >> 4) << 3) + j;
    int n = t * 16 + (l & 15);
    p.dst[wi][idx] = f2bf(p.src[wi][(size_t)k * N + n]);
}

// ---------------- aggregation head (fused into GEMMs) ----------------

__device__ inline void acc8(uint4 v, float* a) {
    a[0] += bf2f(v.x & 0xFFFFu); a[1] += __uint_as_float(v.x & 0xFFFF0000u);
    a[2] += bf2f(v.y & 0xFFFFu); a[3] += __uint_as_float(v.y & 0xFFFF0000u);
    a[4] += bf2f(v.z & 0xFFFFu); a[5] += __uint_as_float(v.z & 0xFFFF0000u);
    a[6] += bf2f(v.w & 0xFFFFu); a[7] += __uint_as_float(v.w & 0xFFFF0000u);
}

// Aggregate BM rows (block tile) directly into the LDS A-tile As[r*(KIN+8)+k]
// (bf16). 8-deep edge pipelining (proven best; 16-deep spilled at the 64-reg
// tier, R7) + 4/2/1 remainder ladder; sequential-e accumulation order.
// Zero rows past M.
template <int BM, int KIN, bool RELU>
__device__ inline void agg_head(const unsigned short* __restrict__ h,
                                const int* __restrict__ rowptr,
                                const int* __restrict__ col,
                                const float* __restrict__ bias,
                                unsigned short* __restrict__ As,
                                int row0, int M, int tid) {
    constexpr int LPN = KIN / 8;       // uint4 lanes per row (16 @128, 8 @64)
    constexpr int GPS = 256 / LPN;     // node groups per sweep
    constexpr int NSW = BM / GPS;      // sweeps to cover BM rows
    constexpr int LDA = KIN + 8;
    const uint4* hv = (const uint4*)h;
    const int l = tid & (LPN - 1);
    const int g = tid / LPN;
#pragma unroll
    for (int sw = 0; sw < NSW; ++sw) {
        int r = sw * GPS + g;
        int node = row0 + r;
        uint4 o = make_uint4(0u, 0u, 0u, 0u);
        if (node < M) {
            float a[8] = {};
            uint4 vs = hv[(size_t)node * LPN + l];  // self (issued early)
            int s = rowptr[node], epos = rowptr[node + 1];
            int e = s;
            for (; e + 8 <= epos; e += 8) {
                int j0 = col[e],     j1 = col[e + 1], j2 = col[e + 2], j3 = col[e + 3];
                int j4 = col[e + 4], j5 = col[e + 5], j6 = col[e + 6], j7 = col[e + 7];
                uint4 v0 = hv[(size_t)j0 * LPN + l];
                uint4 v1 = hv[(size_t)j1 * LPN + l];
                uint4 v2 = hv[(size_t)j2 * LPN + l];
                uint4 v3 = hv[(size_t)j3 * LPN + l];
                uint4 v4 = hv[(size_t)j4 * LPN + l];
                uint4 v5 = hv[(size_t)j5 * LPN + l];
                uint4 v6 = hv[(size_t)j6 * LPN + l];
                uint4 v7 = hv[(size_t)j7 * LPN + l];
                acc8(v0, a); acc8(v1, a); acc8(v2, a); acc8(v3, a);
                acc8(v4, a); acc8(v5, a); acc8(v6, a); acc8(v7, a);
            }
            if (e + 4 <= epos) {
                int j0 = col[e], j1 = col[e + 1], j2 = col[e + 2], j3 = col[e + 3];
                uint4 v0 = hv[(size_t)j0 * LPN + l];
                uint4 v1 = hv[(size_t)j1 * LPN + l];
                uint4 v2 = hv[(size_t)j2 * LPN + l];
                uint4 v3 = hv[(size_t)j3 * LPN + l];
                acc8(v0, a); acc8(v1, a); acc8(v2, a); acc8(v3, a);
                e += 4;
            }
            if (e + 2 <= epos) {
                int j0 = col[e], j1 = col[e + 1];
                uint4 v0 = hv[(size_t)j0 * LPN + l];
                uint4 v1 = hv[(size_t)j1 * LPN + l];
                acc8(v0, a); acc8(v1, a);
                e += 2;
            }
            if (e < epos) acc8(hv[(size_t)col[e] * LPN + l], a);
            acc8(vs, a);
            if (RELU) {
                float4 b0 = *(const float4*)(bias + l * 8);
                float4 b1 = *(const float4*)(bias + l * 8 + 4);
                a[0] = fmaxf(a[0] + b0.x, 0.f); a[1] = fmaxf(a[1] + b0.y, 0.f);
                a[2] = fmaxf(a[2] + b0.z, 0.f); a[3] = fmaxf(a[3] + b0.w, 0.f);
                a[4] = fmaxf(a[4] + b1.x, 0.f); a[5] = fmaxf(a[5] + b1.y, 0.f);
                a[6] = fmaxf(a[6] + b1.z, 0.f); a[7] = fmaxf(a[7] + b1.w, 0.f);
            }
            o.x = (unsigned int)f2bf(a[0]) | ((unsigned int)f2bf(a[1]) << 16);
            o.y = (unsigned int)f2bf(a[2]) | ((unsigned int)f2bf(a[3]) << 16);
            o.z = (unsigned int)f2bf(a[4]) | ((unsigned int)f2bf(a[5]) << 16);
            o.w = (unsigned int)f2bf(a[6]) | ((unsigned int)f2bf(a[7]) << 16);
        }
        *(uint4*)(&As[r * LDA + l * 8]) = o;
    }
}

// ---------------- epilogue scale/shift helper ----------------

__device__ inline void epi_coeff(int mode, int c, const float* bias, const float* g,
                                 const float* be, const float* mu, const float* var,
                                 float* s, float* sh) {
    *s = 1.f; *sh = 0.f;
    if (mode == 0) {
        *sh = bias[c];
    } else if (mode == 1) {
        float t = g[c] * rsqrtf(var[c] + BN_EPS);
        *s = t;
        *sh = be[c] - mu[c] * t + bias[c] * t;
    }
}

// ---------------- bf16 MFMA GEMM v2 (LDS-B; used for L1 fp32-input GEMM) ----

template <int NT, bool F32A>
__global__ __launch_bounds__(256) void mfma_gemm2_kernel(
    const void* __restrict__ Ain, const unsigned short* __restrict__ Wt,
    unsigned short* __restrict__ C,
    int M, int K, int Nn, int mode, int gxblocks, int gy) {
    constexpr int BM = 128, BK = 64;
    constexpr int BN = NT * 16;
    constexpr int LDA = BK + 8;
    constexpr int LDB = BK + 8;
    constexpr int LDE = BN + 8;
    constexpr int NB_LD = (BN * BK / 8) / 256;
    __shared__ __align__(16) unsigned short smem[BM * LDA + BN * LDB];
    unsigned short* As = smem;
    unsigned short* Bs = smem + BM * LDA;
    unsigned short* Ep = smem;

    int id = blockIdx.x;
    int lo = id & 7;
    int t = id >> 3;
    int y = t % gy;
    int x = ((t / gy) << 3) | lo;
    if (x >= gxblocks) return;

    const int tid = threadIdx.x;
    const int wv = tid >> 6;
    const int ln = tid & 63;
    const int l15 = ln & 15;
    const int quad = ln >> 4;
    const int row0 = x * BM;
    const int col0 = y * BN;

    const unsigned short* A16 = (const unsigned short*)Ain;
    const float* A32 = (const float*)Ain;

    uint4 Ar[4], Br[NB_LD];

    auto loadA = [&](int k0) {
#pragma unroll
        for (int u = 0; u < 4; ++u) {
            int idx2 = tid + 256 * u;
            int r = idx2 >> 3, cg = (idx2 & 7) * 8;
            int gr = row0 + r;
            if (gr >= M) gr = M - 1;
            if (F32A) {
                float4 f0 = *(const float4*)(A32 + (size_t)gr * K + k0 + cg);
                float4 f1 = *(const float4*)(A32 + (size_t)gr * K + k0 + cg + 4);
                uint4 o;
                o.x = (unsigned)f2bf(f0.x) | ((unsigned)f2bf(f0.y) << 16);
                o.y = (unsigned)f2bf(f0.z) | ((unsigned)f2bf(f0.w) << 16);
                o.z = (unsigned)f2bf(f1.x) | ((unsigned)f2bf(f1.y) << 16);
                o.w = (unsigned)f2bf(f1.z) | ((unsigned)f2bf(f1.w) << 16);
                Ar[u] = o;
            } else {
                Ar[u] = *(const uint4*)(A16 + (size_t)gr * K + k0 + cg);
            }
        }
    };
    auto loadB = [&](int k0) {
#pragma unroll
        for (int u = 0; u < NB_LD; ++u) {
            int idx2 = tid + 256 * u;
            int r = idx2 >> 3, cg = (idx2 & 7) * 8;
            Br[u] = *(const uint4*)(Wt + (size_t)(col0 + r) * K + k0 + cg);
        }
    };
    auto stage = [&]() {
#pragma unroll
        for (int u = 0; u < 4; ++u) {
            int idx2 = tid + 256 * u;
            int r = idx2 >> 3, cg = (idx2 & 7) * 8;
            *(uint4*)(&As[r * LDA + cg]) = Ar[u];
        }
#pragma unroll
        for (int u = 0; u < NB_LD; ++u) {
            int idx2 = tid + 256 * u;
            int r = idx2 >> 3, cg = (idx2 & 7) * 8;
            *(uint4*)(&Bs[r * LDB + cg]) = Br[u];
        }
    };

    f32x4 acc[2][NT] = {};
    const int KT = K >> 6;
    loadA(0);
    loadB(0);
    for (int kt = 0; kt < KT; ++kt) {
        if (kt > 0) __syncthreads();
        stage();
        __syncthreads();
        if (kt + 1 < KT) {
            loadA((kt + 1) * 64);
            loadB((kt + 1) * 64);
        }
#pragma unroll
        for (int kh = 0; kh < 2; ++kh) {
            bshort8 af[2];
#pragma unroll
            for (int mt = 0; mt < 2; ++mt)
                af[mt] = *(const bshort8*)(&As[(wv * 32 + mt * 16 + l15) * LDA + kh * 32 + quad * 8]);
#pragma unroll
            for (int nt = 0; nt < NT; ++nt) {
                bshort8 bf = *(const bshort8*)(&Bs[(nt * 16 + l15) * LDB + kh * 32 + quad * 8]);
                acc[0][nt] = __builtin_amdgcn_mfma_f32_16x16x32_bf16(af[0], bf, acc[0][nt], 0, 0, 0);
                acc[1][nt] = __builtin_amdgcn_mfma_f32_16x16x32_bf16(af[1], bf, acc[1][nt], 0, 0, 0);
            }
        }
    }

    __syncthreads();
#pragma unroll
    for (int nt = 0; nt < NT; ++nt) {
#pragma unroll
        for (int mt = 0; mt < 2; ++mt) {
            int rl = wv * 32 + mt * 16 + quad * 4;
#pragma unroll
            for (int r = 0; r < 4; ++r) {
                float v = acc[mt][nt][r];
                if (mode != 2) v = fmaxf(v, 0.f);
                Ep[(rl + r) * LDE + nt * 16 + l15] = f2bf(v);
            }
        }
    }
    __syncthreads();
    constexpr int CGR = BN / 8;
    constexpr int NU = BM * CGR / 256;
#pragma unroll
    for (int u = 0; u < NU; ++u) {
        int idx2 = tid + 256 * u;
        int r = idx2 / CGR, cg = (idx2 % CGR) * 8;
        int grow = row0 + r;
        if (grow < M)
            *(uint4*)(C + (size_t)grow * Nn + col0 + cg) = *(const uint4*)(&Ep[r * LDE + cg]);
    }
}

// ---------------- fused agg + single GEMM (BM templated) ----------------
// C = epi( agg(h)+bias,relu  @ W ). No loadA/stage loop: agg_head fills As once.
// BM=64 proven best here (R8: BM=32 hurt the thin kernels).

template <int BM, int KIN, int DH, bool ARELU>
__global__ __launch_bounds__(256, 4) void agg_gemm_kernel(
    const unsigned short* __restrict__ h, const int* __restrict__ rowptr,
    const int* __restrict__ col, const float* __restrict__ abias,
    const unsigned short* __restrict__ Wp,
    int mode, const float* __restrict__ bias, const float* __restrict__ g,
    const float* __restrict__ be, const float* __restrict__ mu, const float* __restrict__ var,
    unsigned short* __restrict__ C, int M) {
    constexpr int MT = BM / 16;
    constexpr int LDA = KIN + 8;
    constexpr int LDE = DH + 8;
    constexpr int NT = DH / 64;
    constexpr int S = KIN / 32;
    constexpr int LMX = (LDA > LDE) ? LDA : LDE;
    __shared__ __align__(16) unsigned short smem[BM * LMX];
    unsigned short* As = smem;
    unsigned short* Ep = smem;

    const int tid = threadIdx.x;
    const int wv = tid >> 6;
    const int ln = tid & 63;
    const int l15 = ln & 15;
    const int quad = ln >> 4;
    const int tb = wv * NT;
    const int ch = wv * (DH / 4);
    const int row0 = blockIdx.x * BM;

    auto loadB = [&](int s, bshort8* d) {
#pragma unroll
        for (int nt = 0; nt < NT; ++nt)
            d[nt] = *(const bshort8*)(Wp + ((size_t)((tb + nt) * S + s) * 64 + ln) * 8);
    };

    bshort8 bf[NT], bnx[NT];
    loadB(0, bf);  // in flight under the gather phase (used right after; short live range)
    agg_head<BM, KIN, ARELU>(h, rowptr, col, abias, As, row0, M, tid);
    __syncthreads();

    f32x4 acc[MT][NT] = {};
#pragma unroll
    for (int ks = 0; ks < S; ++ks) {
        if (ks + 1 < S) loadB(ks + 1, bnx);
        bshort8 af[MT];
#pragma unroll
        for (int mt = 0; mt < MT; ++mt)
            af[mt] = *(const bshort8*)(&As[(mt * 16 + l15) * LDA + ks * 32 + quad * 8]);
#pragma unroll
        for (int nt = 0; nt < NT; ++nt)
#pragma unroll
            for (int mt = 0; mt < MT; ++mt)
                acc[mt][nt] = __builtin_amdgcn_mfma_f32_16x16x32_bf16(af[mt], bf[nt], acc[mt][nt], 0, 0, 0);
        if (ks + 1 < S) {
#pragma unroll
            for (int nt = 0; nt < NT; ++nt) bf[nt] = bnx[nt];
        }
    }
    __syncthreads();  // As dead; Ep overlay safe
#pragma unroll
    for (int nt = 0; nt < NT; ++nt) {
        int c = ch + nt * 16 + l15;
        float s, sh;
        epi_coeff(mode, c, bias, g, be, mu, var, &s, &sh);
#pragma unroll
        for (int mt = 0; mt < MT; ++mt) {
            int rl = mt * 16 + quad * 4;
#pragma unroll
            for (int r = 0; r < 4; ++r) {
                float v = acc[mt][nt][r] * s + sh;
                if (mode != 2) v = fmaxf(v, 0.f);
                Ep[(rl + r) * LDE + c] = f2bf(v);
            }
        }
    }
    __syncthreads();
    constexpr int CGR = DH / 8;
    constexpr int NU = BM * CGR / 256;
#pragma unroll
    for (int u = 0; u < NU; ++u) {
        int idx2 = tid + 256 * u;
        int r = idx2 / CGR, cg = (idx2 % CGR) * 8;
        int grow = row0 + r;
        if (grow < M)
            *(uint4*)(C + (size_t)grow * DH + cg) = *(const uint4*)(&Ep[r * LDE + cg]);
    }
}

// ---------------- fused agg + 2-stage MLP (BM templated) ----------------
// C = epi2( epi1( (agg(h)[+bias,relu]) @ W1 ) @ W2 ). As/T1/Ep overlay.
// BM=64 for the thin <128,128,64> instance (R8: 32 hurt it).
// bf2 loaded late (short live range, R6).

template <int BM, int KIN, int DH1, int DH2, bool ARELU>
__global__ __launch_bounds__(256, 4) void agg_mlp_kernel(
    const unsigned short* __restrict__ h, const int* __restrict__ rowptr,
    const int* __restrict__ col, const float* __restrict__ abias,
    const unsigned short* __restrict__ Wp1, const unsigned short* __restrict__ Wp2,
    int mode1, const float* __restrict__ b1, const float* __restrict__ g1,
    const float* __restrict__ be1, const float* __restrict__ mu1, const float* __restrict__ var1,
    int mode2, const float* __restrict__ b2, const float* __restrict__ g2,
    const float* __restrict__ be2, const float* __restrict__ mu2, const float* __restrict__ var2,
    unsigned short* __restrict__ C, int M) {
    constexpr int MT = BM / 16;
    constexpr int LDA = KIN + 8;
    constexpr int LT1 = DH1 + 8;
    constexpr int LDE = DH2 + 8;
    constexpr int NT1 = DH1 / 64;
    constexpr int NT2 = DH2 / 64;
    constexpr int S1 = KIN / 32;
    constexpr int S2 = DH1 / 32;
    constexpr int LM0 = (LDA > LT1) ? LDA : LT1;
    constexpr int LMX = (LM0 > LDE) ? LM0 : LDE;
    __shared__ __align__(16) unsigned short smem[BM * LMX];
    unsigned short* As = smem;
    unsigned short* T1 = smem;

    const int tid = threadIdx.x;
    const int wv = tid >> 6;
    const int ln = tid & 63;
    const int l15 = ln & 15;
    const int quad = ln >> 4;
    const int tb1 = wv * NT1;
    const int tb2 = wv * NT2;
    const int ch1 = wv * (DH1 / 4);
    const int ch2 = wv * (DH2 / 4);
    const int row0 = blockIdx.x * BM;

    auto loadB1 = [&](int s, bshort8* d) {
#pragma unroll
        for (int nt = 0; nt < NT1; ++nt)
            d[nt] = *(const bshort8*)(Wp1 + ((size_t)((tb1 + nt) * S1 + s) * 64 + ln) * 8);
    };
    auto loadB2 = [&](int s, bshort8* d) {
#pragma unroll
        for (int nt = 0; nt < NT2; ++nt)
            d[nt] = *(const bshort8*)(Wp2 + ((size_t)((tb2 + nt) * S2 + s) * 64 + ln) * 8);
    };

    bshort8 bf[NT1], bnx[NT1], bf2[NT2];
    loadB1(0, bf);
    agg_head<BM, KIN, ARELU>(h, rowptr, col, abias, As, row0, M, tid);
    __syncthreads();

    // ---- stage 1: A from As (LDS-resident, no restaging) ----
    f32x4 acc1[MT][NT1] = {};
#pragma unroll
    for (int ks = 0; ks < S1; ++ks) {
        if (ks + 1 < S1) loadB1(ks + 1, bnx);
        bshort8 af[MT];
#pragma unroll
        for (int mt = 0; mt < MT; ++mt)
            af[mt] = *(const bshort8*)(&As[(mt * 16 + l15) * LDA + ks * 32 + quad * 8]);
#pragma unroll
        for (int nt = 0; nt < NT1; ++nt)
#pragma unroll
            for (int mt = 0; mt < MT; ++mt)
                acc1[mt][nt] = __builtin_amdgcn_mfma_f32_16x16x32_bf16(af[mt], bf[nt], acc1[mt][nt], 0, 0, 0);
        if (ks + 1 < S1) {
#pragma unroll
            for (int nt = 0; nt < NT1; ++nt) bf[nt] = bnx[nt];
        }
    }
    __syncthreads();  // As dead; T1 overlay safe
    // epi1 -> T1 (LDS)
#pragma unroll
    for (int nt = 0; nt < NT1; ++nt) {
        int c = ch1 + nt * 16 + l15;
        float s, sh;
        epi_coeff(mode1, c, b1, g1, be1, mu1, var1, &s, &sh);
#pragma unroll
        for (int mt = 0; mt < MT; ++mt) {
            int rl = mt * 16 + quad * 4;
#pragma unroll
            for (int r = 0; r < 4; ++r) {
                float v = acc1[mt][nt][r] * s + sh;
                if (mode1 != 2) v = fmaxf(v, 0.f);
                T1[(rl + r) * LT1 + c] = f2bf(v);
            }
        }
    }
    loadB2(0, bf2);  // issue stage-2 B0 load; latency hides under the barrier + epi drain
    __syncthreads();

    // ---- stage 2: A from T1 (LDS), B depth-1 pipelined, barrier-free loop ----
    f32x4 acc2[MT][NT2] = {};
    bshort8 bnx2[NT2];
#pragma unroll
    for (int ks = 0; ks < S2; ++ks) {
        if (ks + 1 < S2) loadB2(ks + 1, bnx2);
        bshort8 af[MT];
#pragma unroll
        for (int mt = 0; mt < MT; ++mt)
            af[mt] = *(const bshort8*)(&T1[(mt * 16 + l15) * LT1 + ks * 32 + quad * 8]);
#pragma unroll
        for (int nt = 0; nt < NT2; ++nt)
#pragma unroll
            for (int mt = 0; mt < MT; ++mt)
                acc2[mt][nt] = __builtin_amdgcn_mfma_f32_16x16x32_bf16(af[mt], bf2[nt], acc2[mt][nt], 0, 0, 0);
        if (ks + 1 < S2) {
#pragma unroll
            for (int nt = 0; nt < NT2; ++nt) bf2[nt] = bnx2[nt];
        }
    }
    __syncthreads();  // T1 dead; Ep overlay safe

    unsigned short* Ep = T1;
#pragma unroll
    for (int nt = 0; nt < NT2; ++nt) {
        int c = ch2 + nt * 16 + l15;
        float s, sh;
        epi_coeff(mode2, c, b2, g2, be2, mu2, var2, &s, &sh);
#pragma unroll
        for (int mt = 0; mt < MT; ++mt) {
            int rl = mt * 16 + quad * 4;
#pragma unroll
            for (int r = 0; r < 4; ++r) {
                float v = acc2[mt][nt][r] * s + sh;
                if (mode2 != 2) v = fmaxf(v, 0.f);
                Ep[(rl + r) * LDE + c] = f2bf(v);
            }
        }
    }
    __syncthreads();
    constexpr int CGR = DH2 / 8;
    constexpr int NU = BM * CGR / 256;
#pragma unroll
    for (int u = 0; u < NU; ++u) {
        int idx2 = tid + 256 * u;
        int r = idx2 / CGR, cg = (idx2 % CGR) * 8;
        int grow = row0 + r;
        if (grow < M)
            *(uint4*)(C + (size_t)grow * DH2 + cg) = *(const uint4*)(&Ep[r * LDE + cg]);
    }
}

// ---------------- fused agg + 3-stage MLP (L2 + L3-G1 folded) ----------------
// C = W3( epi2( epi1( (agg(h)) @ W1 ) @ W2 ) )  [mode3=2 raw].
// Exploits agg(h)@W = agg(h@W) linearity downstream: h2 never hits global.
// As/T1/T2/Ep all overlay one buffer (barrier-separated). R10: 60 VGPR,
// no spill, WRITE 12.5MB, -10us total.

template <int BM, int KIN, int DH1, int DH2, int DH3, bool ARELU>
__global__ __launch_bounds__(256, 4) void agg_mlp3_kernel(
    const unsigned short* __restrict__ h, const int* __restrict__ rowptr,
    const int* __restrict__ col, const float* __restrict__ abias,
    const unsigned short* __restrict__ Wp1, const unsigned short* __restrict__ Wp2,
    const unsigned short* __restrict__ Wp3,
    int mode1, const float* __restrict__ b1, const float* __restrict__ g1,
    const float* __restrict__ be1, const float* __restrict__ mu1, const float* __restrict__ var1,
    int mode2, const float* __restrict__ b2, const float* __restrict__ g2,
    const float* __restrict__ be2, const float* __restrict__ mu2, const float* __restrict__ var2,
    unsigned short* __restrict__ C, int M) {
    constexpr int MT = BM / 16;
    constexpr int LDA = KIN + 8;
    constexpr int LT1 = DH1 + 8;
    constexpr int LT2 = DH2 + 8;
    constexpr int LDE = DH3 + 8;
    constexpr int NT1 = DH1 / 64;
    constexpr int NT2 = DH2 / 64;
    constexpr int NT3 = DH3 / 64;
    constexpr int S1 = KIN / 32;
    constexpr int S2 = DH1 / 32;
    constexpr int S3 = DH2 / 32;
    constexpr int LM0 = (LDA > LT1) ? LDA : LT1;
    constexpr int LM1 = (LM0 > LT2) ? LM0 : LT2;
    constexpr int LMX = (LM1 > LDE) ? LM1 : LDE;
    __shared__ __align__(16) unsigned short smem[BM * LMX];
    unsigned short* As = smem;
    unsigned short* T1 = smem;
    unsigned short* T2 = smem;

    const int tid = threadIdx.x;
    const int wv = tid >> 6;
    const int ln = tid & 63;
    const int l15 = ln & 15;
    const int quad = ln >> 4;
    const int tb1 = wv * NT1;
    const int tb2 = wv * NT2;
    const int tb3 = wv * NT3;
    const int ch1 = wv * (DH1 / 4);
    const int ch2 = wv * (DH2 / 4);
    const int ch3 = wv * (DH3 / 4);
    const int row0 = blockIdx.x * BM;

    auto loadB1 = [&](int s, bshort8* d) {
#pragma unroll
        for (int nt = 0; nt < NT1; ++nt)
            d[nt] = *(const bshort8*)(Wp1 + ((size_t)((tb1 + nt) * S1 + s) * 64 + ln) * 8);
    };
    auto loadB2 = [&](int s, bshort8* d) {
#pragma unroll
        for (int nt = 0; nt < NT2; ++nt)
            d[nt] = *(const bshort8*)(Wp2 + ((size_t)((tb2 + nt) * S2 + s) * 64 + ln) * 8);
    };
    auto loadB3 = [&](int s, bshort8* d) {
#pragma unroll
        for (int nt = 0; nt < NT3; ++nt)
            d[nt] = *(const bshort8*)(Wp3 + ((size_t)((tb3 + nt) * S3 + s) * 64 + ln) * 8);
    };

    bshort8 bf[NT1], bnx[NT1];
    loadB1(0, bf);
    agg_head<BM, KIN, ARELU>(h, rowptr, col, abias, As, row0, M, tid);
    __syncthreads();

    // ---- stage 1: A = As (agg output) ----
    f32x4 acc1[MT][NT1] = {};
#pragma unroll
    for (int ks = 0; ks < S1; ++ks) {
        if (ks + 1 < S1) loadB1(ks + 1, bnx);
        bshort8 af[MT];
#pragma unroll
        for (int mt = 0; mt < MT; ++mt)
            af[mt] = *(const bshort8*)(&As[(mt * 16 + l15) * LDA + ks * 32 + quad * 8]);
#pragma unroll
        for (int nt = 0; nt < NT1; ++nt)
#pragma unroll
            for (int mt = 0; mt < MT; ++mt)
                acc1[mt][nt] = __builtin_amdgcn_mfma_f32_16x16x32_bf16(af[mt], bf[nt], acc1[mt][nt], 0, 0, 0);
        if (ks + 1 < S1) {
#pragma unroll
            for (int nt = 0; nt < NT1; ++nt) bf[nt] = bnx[nt];
        }
    }
    __syncthreads();  // As dead; T1 overlay safe
#pragma unroll
    for (int nt = 0; nt < NT1; ++nt) {
        int c = ch1 + nt * 16 + l15;
        float s, sh;
        epi_coeff(mode1, c, b1, g1, be1, mu1, var1, &s, &sh);
#pragma unroll
        for (int mt = 0; mt < MT; ++mt) {
            int rl = mt * 16 + quad * 4;
#pragma unroll
            for (int r = 0; r < 4; ++r) {
                float v = acc1[mt][nt][r] * s + sh;
                if (mode1 != 2) v = fmaxf(v, 0.f);
                T1[(rl + r) * LT1 + c] = f2bf(v);
            }
        }
    }
    bshort8 bf2[NT2], bnx2[NT2];
    loadB2(0, bf2);  // latency hides under the barrier
    __syncthreads();

    // ---- stage 2: A = T1 ----
    f32x4 acc2[MT][NT2] = {};
#pragma unroll
    for (int ks = 0; ks < S2; ++ks) {
        if (ks + 1 < S2) loadB2(ks + 1, bnx2);
        bshort8 af[MT];
#pragma unroll
        for (int mt = 0; mt < MT; ++mt)
            af[mt] = *(const bshort8*)(&T1[(mt * 16 + l15) * LT1 + ks * 32 + quad * 8]);
#pragma unroll
        for (int nt = 0; nt < NT2; ++nt)
#pragma unroll
            for (int mt = 0; mt < MT; ++mt)
                acc2[mt][nt] = __builtin_amdgcn_mfma_f32_16x16x32_bf16(af[mt], bf2[nt], acc2[mt][nt], 0, 0, 0);
        if (ks + 1 < S2) {
#pragma unroll
            for (int nt = 0; nt < NT2; ++nt) bf2[nt] = bnx2[nt];
        }
    }
    __syncthreads();  // T1 dead; T2 overlay safe
#pragma unroll
    for (int nt = 0; nt < NT2; ++nt) {
        int c = ch2 + nt * 16 + l15;
        float s, sh;
        epi_coeff(mode2, c, b2, g2, be2, mu2, var2, &s, &sh);
#pragma unroll
        for (int mt = 0; mt < MT; ++mt) {
            int rl = mt * 16 + quad * 4;
#pragma unroll
            for (int r = 0; r < 4; ++r) {
                float v = acc2[mt][nt][r] * s + sh;
                if (mode2 != 2) v = fmaxf(v, 0.f);
                T2[(rl + r) * LT2 + c] = f2bf(v);
            }
        }
    }
    bshort8 bf3[NT3], bnx3[NT3];
    loadB3(0, bf3);
    __syncthreads();

    // ---- stage 3: A = T2, raw output (mode 2) ----
    f32x4 acc3[MT][NT3] = {};
#pragma unroll
    for (int ks = 0; ks < S3; ++ks) {
        if (ks + 1 < S3) loadB3(ks + 1, bnx3);
        bshort8 af[MT];
#pragma unroll
        for (int mt = 0; mt < MT; ++mt)
            af[mt] = *(const bshort8*)(&T2[(mt * 16 + l15) * LT2 + ks * 32 + quad * 8]);
#pragma unroll
        for (int nt = 0; nt < NT3; ++nt)
#pragma unroll
            for (int mt = 0; mt < MT; ++mt)
                acc3[mt][nt] = __builtin_amdgcn_mfma_f32_16x16x32_bf16(af[mt], bf3[nt], acc3[mt][nt], 0, 0, 0);
        if (ks + 1 < S3) {
#pragma unroll
            for (int nt = 0; nt < NT3; ++nt) bf3[nt] = bnx3[nt];
        }
    }
    __syncthreads();  // T2 dead; Ep overlay safe

    unsigned short* Ep = smem;
#pragma unroll
    for (int nt = 0; nt < NT3; ++nt) {
        int c = ch3 + nt * 16 + l15;
#pragma unroll
        for (int mt = 0; mt < MT; ++mt) {
            int rl = mt * 16 + quad * 4;
#pragma unroll
            for (int r = 0; r < 4; ++r)
                Ep[(rl + r) * LDE + c] = f2bf(acc3[mt][nt][r]);  // raw
        }
    }
    __syncthreads();
    constexpr int CGR = DH3 / 8;
    constexpr int NU = BM * CGR / 256;
#pragma unroll
    for (int u = 0; u < NU; ++u) {
        int idx2 = tid + 256 * u;
        int r = idx2 / CGR, cg = (idx2 % CGR) * 8;
        int grow = row0 + r;
        if (grow < M)
            *(uint4*)(C + (size_t)grow * DH3 + cg) = *(const uint4*)(&Ep[r * LDE + cg]);
    }
}

// ---------------- fused agg + GEMM + classifier (L4 tail, BM=64) ----------------
// out = epi_bn( (relu(agg(h)+b4a)) @ W ) @ wc + bc.  KIN=DH=64.

__global__ __launch_bounds__(256, 4) void agg_cls_kernel(
    const unsigned short* __restrict__ h, const int* __restrict__ rowptr,
    const int* __restrict__ col, const float* __restrict__ abias,
    const unsigned short* __restrict__ Wp,
    const float* __restrict__ bias, const float* __restrict__ g,
    const float* __restrict__ be, const float* __restrict__ mu, const float* __restrict__ var,
    const float* __restrict__ wcls, const float* __restrict__ bcls,
    float* __restrict__ outp, int M) {
    constexpr int BM = 64, KIN = 64, DH = 64;
    constexpr int LDA = KIN + 8;
    constexpr int LDE = DH + 8;
    constexpr int NT = 1;
    constexpr int S = KIN / 32;
    __shared__ __align__(16) unsigned short smem[BM * LDA];
    unsigned short* As = smem;
    unsigned short* Ep = smem;

    const int tid = threadIdx.x;
    const int wv = tid >> 6;
    const int ln = tid & 63;
    const int l15 = ln & 15;
    const int quad = ln >> 4;
    const int tb = wv;              // NT=1
    const int ch = wv * 16;
    const int row0 = blockIdx.x * BM;

    auto loadB = [&](int s, bshort8* d) {
        d[0] = *(const bshort8*)(Wp + ((size_t)(tb * S + s) * 64 + ln) * 8);
    };

    bshort8 bf[NT], bnx[NT];
    loadB(0, bf);
    agg_head<BM, KIN, true>(h, rowptr, col, abias, As, row0, M, tid);
    __syncthreads();

    f32x4 acc[4][NT] = {};
#pragma unroll
    for (int ks = 0; ks < S; ++ks) {
        if (ks + 1 < S) loadB(ks + 1, bnx);
        bshort8 af[4];
#pragma unroll
        for (int mt = 0; mt < 4; ++mt)
            af[mt] = *(const bshort8*)(&As[(mt * 16 + l15) * LDA + ks * 32 + quad * 8]);
#pragma unroll
        for (int mt = 0; mt < 4; ++mt)
            acc[mt][0] = __builtin_amdgcn_mfma_f32_16x16x32_bf16(af[mt], bf[0], acc[mt][0], 0, 0, 0);
        if (ks + 1 < S) bf[0] = bnx[0];
    }
    __syncthreads();  // As dead; Ep overlay safe
    {
        int c = ch + l15;
        float s, sh;
        epi_coeff(1, c, bias, g, be, mu, var, &s, &sh);
#pragma unroll
        for (int mt = 0; mt < 4; ++mt) {
            int rl = mt * 16 + quad * 4;
#pragma unroll
            for (int r = 0; r < 4; ++r) {
                float v = fmaxf(acc[mt][0][r] * s + sh, 0.f);
                Ep[(rl + r) * LDE + c] = f2bf(v);
            }
        }
    }
    __syncthreads();
    if (tid < 128) {
        int r = tid >> 1, j = tid & 1;
        int grow = row0 + r;
        if (grow < M) {
            float s = 0.f;
#pragma unroll 8
            for (int k = 0; k < 64; ++k)
                s += bf2f(Ep[r * LDE + k]) * wcls[k * 2 + j];
            outp[(size_t)grow * 2 + j] = s + bcls[j];
        }
    }
}

// ---------------- launch ----------------

extern "C" void kernel_launch(void* const* d_in, const int* in_sizes, int n_in,
                              void* d_out, int out_size, void* d_ws, size_t ws_size,
                              hipStream_t stream) {
    const float* x = (const float*)d_in[0];
    const int* ei = (const int*)d_in[1];
    const int* src = ei;
    const int* dst = ei + N_EDGES;
    const float* w[4][2];
    const float* b[4][2];
    const float* bng[4];
    const float* bnb[4];
    const float* bnm[4];
    const float* bnv[4];
    int idx = 2;
    for (int i = 0; i < 4; ++i) {
        w[i][0] = (const float*)d_in[idx++];
        b[i][0] = (const float*)d_in[idx++];
        w[i][1] = (const float*)d_in[idx++];
        b[i][1] = (const float*)d_in[idx++];
        bng[i] = (const float*)d_in[idx++];
        bnb[i] = (const float*)d_in[idx++];
        bnm[i] = (const float*)d_in[idx++];
        bnv[i] = (const float*)d_in[idx++];
    }
    const float* wc = (const float*)d_in[idx++];
    const float* bc = (const float*)d_in[idx++];
    float* out = (float*)d_out;

    char* ws = (char*)d_ws;
    size_t off = 0;
    auto alloc = [&](size_t bytes) {
        char* p = ws + off;
        off = (off + bytes + 255) & ~(size_t)255;
        return p;
    };
    int* deg = (int*)alloc((size_t)N_NODES * 4);
    int* rowptr = (int*)alloc((size_t)(N_NODES + 1) * 4);
    int* cnt = (int*)alloc((size_t)K_BUCK * PART_B * 4);
    int* bsum2 = (int*)alloc((size_t)K_BUCK * 4);
    int* col = (int*)alloc((size_t)N_EDGES * 4 + 64);   // +64B pad: 8-wide col reads may touch past row end
    uint2* P = (uint2*)alloc((size_t)N_EDGES * 8);
    unsigned short* bufA = (unsigned short*)alloc((size_t)N_NODES * 256 * 2);
    unsigned short* bufB = (unsigned short*)alloc((size_t)N_NODES * 256 * 2);
    unsigned short* bufC = (unsigned short*)alloc((size_t)N_NODES * 256 * 2);
    const int dims_in[4] = {256, 128, 256, 128};
    const int dims_h[4] = {128, 256, 128, 64};
    unsigned short* wt[4][2];
    unsigned short* wp[4][2];
    for (int L = 0; L < 4; ++L) {
        wt[L][0] = (unsigned short*)alloc((size_t)dims_in[L] * dims_h[L] * 2);
        wt[L][1] = (unsigned short*)alloc((size_t)dims_h[L] * dims_h[L] * 2);
        wp[L][0] = (unsigned short*)alloc((size_t)dims_in[L] * dims_h[L] * 2);
        wp[L][1] = (unsigned short*)alloc((size_t)dims_h[L] * dims_h[L] * 2);
    }
    (void)ws_size;

    // weight conversions: row-major transposed (wt) + fragment-packed (wp)
    WT8 p;
    for (int L = 0; L < 4; ++L) {
        p.src[L * 2] = w[L][0];     p.dst[L * 2] = wt[L][0];
        p.K[L * 2] = dims_in[L];    p.N[L * 2] = dims_h[L];
        p.src[L * 2 + 1] = w[L][1]; p.dst[L * 2 + 1] = wt[L][1];
        p.K[L * 2 + 1] = dims_h[L]; p.N[L * 2 + 1] = dims_h[L];
    }
    wtconv_kernel<<<dim3(256, 8), 256, 0, stream>>>(p);
    WT8 q = p;
    for (int L = 0; L < 4; ++L) {
        q.dst[L * 2] = wp[L][0];
        q.dst[L * 2 + 1] = wp[L][1];
    }
    wpconv_kernel<<<dim3(256, 8), 256, 0, stream>>>(q);

    // ---- CSR build ----
    hipMemsetAsync(deg, 0, (size_t)N_NODES * 4, stream);
    bucket_count_kernel<<<PART_B, 256, 0, stream>>>(dst, deg, cnt);
    scan_reduce_kernel<<<K_BUCK, 256, 0, stream>>>(cnt, bsum2, K_BUCK * PART_B);
    scan_bsum_kernel<<<1, 256, 0, stream>>>(bsum2, K_BUCK);
    scan_apply_kernel<<<K_BUCK, 256, 0, stream>>>(cnt, bsum2, cnt, K_BUCK * PART_B);
    partition_kernel<<<PART_B, 256, 0, stream>>>(src, dst, cnt, P);
    fine_scatter_kernel<<<K_BUCK, 256, 0, stream>>>(P, cnt, deg, rowptr, col);

    const int gx = (N_NODES + 127) / 128;       // 391
    const int gxp = ((gx + 7) / 8) * 8;         // 392
    const int gx32 = (N_NODES + 31) / 32;       // 1563
    const int gx64 = (N_NODES + 63) / 64;       // 782
    const int M = N_NODES;

    // ---- L1-G1: x @ w1a (fp32 A, 256->128, raw) -> bufA ----
    mfma_gemm2_kernel<8, true><<<gxp, 256, 0, stream>>>(
        x, wt[0][0], bufA, M, 256, 128, 2, gx, 1);

    // ---- L1: [agg(bufA)+b1a,relu] @ w1b -> BN+relu -> bufC (h1) ----
    agg_gemm_kernel<64, 128, 128, true><<<gx64, 256, 0, stream>>>(
        bufA, rowptr, col, b[0][0], wp[0][1],
        1, b[0][1], bng[0], bnb[0], bnm[0], bnv[0], bufC, M);

    // ---- L2 + L3-G1 fused: [agg(bufC)] @ w2a+b2a relu @ w2b BN relu @ w3a raw -> bufA ----
    agg_mlp3_kernel<32, 128, 256, 256, 128, false><<<gx32, 256, 0, stream>>>(
        bufC, rowptr, col, nullptr, wp[1][0], wp[1][1], wp[2][0],
        0, b[1][0], nullptr, nullptr, nullptr, nullptr,
        1, b[1][1], bng[1], bnb[1], bnm[1], bnv[1],
        bufA, M);

    // ---- L3/L4: [agg(bufA)+b3a,relu] @ w3b BN+relu -> @ w4a raw -> bufB ----
    agg_mlp_kernel<64, 128, 128, 64, true><<<gx64, 256, 0, stream>>>(
        bufA, rowptr, col, b[2][0], wp[2][1], wp[3][0],
        1, b[2][1], bng[2], bnb[2], bnm[2], bnv[2],
        2, nullptr, nullptr, nullptr, nullptr, nullptr,
        bufB, M);

    // ---- L4 tail: [agg(bufB)+b4a,relu] @ w4b BN+relu -> classifier -> out ----
    agg_cls_kernel<<<gx64, 256, 0, stream>>>(
        bufB, rowptr, col, b[3][0], wp[3][1],
        b[3][1], bng[3], bnb[3], bnm[3], bnv[3], wc, bc, out, M);
}